// Round 1
// baseline (444.563 us; speedup 1.0000x reference)
//
#include <hip/hip_runtime.h>

// CrossAttention: B=4, C=256, H=W=64, N=4096, fp32 in/out.
// ws layout (needs ~42 MB):
//   Qhi [B,N,C] bf16 @0MB, Qlo @8MB, Khi @16MB, Klo @24MB, Vt [B,C,N] bf16 @32MB, WT [3][C][C] f32 @40MB

typedef __attribute__((ext_vector_type(8))) short short8;
typedef __attribute__((ext_vector_type(4))) short short4v;
typedef __attribute__((ext_vector_type(4))) float f32x4;
typedef __attribute__((ext_vector_type(4))) int int4v;

#define LOG2E 1.44269504089f

static __device__ __forceinline__ float exp2_fast(float x){ return __builtin_amdgcn_exp2f(x); }

static __device__ __forceinline__ int cvt_pk_bf16(float lo, float hi){
  int r; asm("v_cvt_pk_bf16_f32 %0, %1, %2" : "=v"(r) : "v"(lo), "v"(hi)); return r;
}

static __device__ __forceinline__ unsigned short f2bf(float f){
  unsigned u = __builtin_bit_cast(unsigned, f);
  u = u + 0x7FFFu + ((u >> 16) & 1u);          // round-to-nearest-even
  return (unsigned short)(u >> 16);
}
static __device__ __forceinline__ float bf2f(unsigned short h){
  unsigned u = ((unsigned)h) << 16;
  return __builtin_bit_cast(float, u);
}

#define GLOAD16(gp, lp) __builtin_amdgcn_global_load_lds( \
  (const __attribute__((address_space(1))) void*)(gp),    \
  (__attribute__((address_space(3))) void*)(lp), 16, 0, 0)

#define MFMA16(a,b,c) __builtin_amdgcn_mfma_f32_16x16x32_bf16(a,b,c,0,0,0)

// ---------------------------------------------------------------- transpose W
__global__ __launch_bounds__(256) void transpose_w(
    const float* __restrict__ wq, const float* __restrict__ wk,
    const float* __restrict__ wv, float* __restrict__ wt)
{
  const int o = blockIdx.x;          // 0..255
  const int t = blockIdx.y;          // 0..2
  const int c = threadIdx.x;         // 0..255
  const float* w = (t == 0) ? wq : ((t == 1) ? wk : wv);
  wt[t*65536 + c*256 + o] = w[o*256 + c];   // WT[t][c][o] = W[o][c]
}

// ---------------------------------------------------------------- projections
// q[b,n,o] = sum_c Wq[o,c] x[b,c,n] + bq[o]   (same for k,v from y)
// t=0 -> Qhi/Qlo; t=1 -> Khi/Klo; t=2 -> Vt (transposed [B,C,N])
__global__ __launch_bounds__(256) void proj_kernel(
    const float* __restrict__ x, const float* __restrict__ y,
    const float* __restrict__ wt,
    const float* __restrict__ bq, const float* __restrict__ bk, const float* __restrict__ bv,
    unsigned short* __restrict__ qhi, unsigned short* __restrict__ qlo,
    unsigned short* __restrict__ khi, unsigned short* __restrict__ klo,
    unsigned short* __restrict__ vt)
{
  const int t  = blockIdx.z;
  const int b  = blockIdx.y;
  const int n0 = blockIdx.x * 64;
  const int tid = threadIdx.x;
  const int oi = tid & 63;       // 64 o-groups of 4 -> o = oi*4+a (coalesced W reads/stores)
  const int gq = tid >> 6;       // wave id -> n = n0 + gq*16 + j (broadcast x reads)

  const float* src  = (t == 0) ? x : y;
  const float* wtt  = wt + t * 65536;
  const float* bias = (t == 0) ? bq : ((t == 1) ? bk : bv);

  f32x4 bias4 = *(const f32x4*)&bias[oi*4];

  float acc[4][16];
  #pragma unroll
  for (int a=0;a<4;a++)
    #pragma unroll
    for (int j=0;j<16;j++) acc[a][j] = 0.f;

  const float* xbase = src + ((size_t)b*256)*4096 + n0 + gq*16;
  for (int c=0;c<256;c++){
    f32x4 wv4 = *(const f32x4*)&wtt[c*256 + oi*4];
    f32x4 xv0 = *(const f32x4*)&xbase[(size_t)c*4096 + 0];
    f32x4 xv1 = *(const f32x4*)&xbase[(size_t)c*4096 + 4];
    f32x4 xv2 = *(const f32x4*)&xbase[(size_t)c*4096 + 8];
    f32x4 xv3 = *(const f32x4*)&xbase[(size_t)c*4096 + 12];
    #pragma unroll
    for (int a=0;a<4;a++){
      float wa = wv4[a];
      #pragma unroll
      for (int j=0;j<4;j++){
        acc[a][j]    += wa * xv0[j];
        acc[a][4+j]  += wa * xv1[j];
        acc[a][8+j]  += wa * xv2[j];
        acc[a][12+j] += wa * xv3[j];
      }
    }
  }

  if (t < 2){
    unsigned short* hi_out = (t==0) ? qhi : khi;
    unsigned short* lo_out = (t==0) ? qlo : klo;
    #pragma unroll
    for (int j=0;j<16;j++){
      int n = n0 + gq*16 + j;
      short4v hv, lv;
      #pragma unroll
      for (int a=0;a<4;a++){
        float v = acc[a][j] + bias4[a];
        unsigned short h = f2bf(v);
        float r = v - bf2f(h);
        hv[a] = (short)h;
        lv[a] = (short)f2bf(r);
      }
      size_t off = ((size_t)(b*4096 + n))*256 + oi*4;
      *(short4v*)&hi_out[off] = hv;
      *(short4v*)&lo_out[off] = lv;
    }
  } else {
    #pragma unroll
    for (int a=0;a<4;a++){
      int o = oi*4 + a;
      float bb = bias4[a];
      short8 v0, v1;
      #pragma unroll
      for (int j=0;j<8;j++){
        v0[j] = (short)f2bf(acc[a][j]   + bb);
        v1[j] = (short)f2bf(acc[a][8+j] + bb);
      }
      size_t off = ((size_t)(b*256 + o))*4096 + n0 + gq*16;
      *(short8*)&vt[off]     = v0;
      *(short8*)&vt[off + 8] = v1;
    }
  }
}

// ---------------------------------------------------------------- attention
// grid (64 n-tiles, 4 batches), 256 thr = 4 waves x 16 q-rows.
// Per KV-tile of 32: S^T = K*Q^T via mfma (3-term bf16x2 split), in-register
// online softmax (n = lane&15 is lane-local), P transposed to PV B-frag via
// bpermute, O^T = V^T * P^T accumulate. K/V staged to LDS with
// global_load_lds, XOR-swizzled (pre-swizzled global source), double-buffered.
__global__ __launch_bounds__(256, 1) void attn_kernel(
    const unsigned short* __restrict__ qhi, const unsigned short* __restrict__ qlo,
    const unsigned short* __restrict__ khi, const unsigned short* __restrict__ klo,
    const unsigned short* __restrict__ vt,
    float* __restrict__ out)
{
  __shared__ short kh_s[2][32*256];   // [buf][m][c] bf16, rows 512B, swz ^((m&7)<<4)
  __shared__ short kl_s[2][32*256];
  __shared__ short v_s [2][256*32];   // [buf][c][m] bf16, rows 64B, swz ^(((c>>1)&3)<<4)

  const int tid  = threadIdx.x;
  const int w    = tid >> 6;
  const int lane = tid & 63;
  const int g    = lane >> 4;
  const int col  = lane & 15;          // = this lane's n (as MFMA B-col) and c-row for V
  const int b    = blockIdx.y;
  const int n0   = blockIdx.x * 64;

  // Q fragments in registers: Q[n][c], n = n0+w*16+col, 8 contiguous c per chunk
  short8 qh[8], ql[8];
  {
    const size_t qoff = ((size_t)(b*4096 + n0 + w*16 + col))*256 + g*8;
    #pragma unroll
    for (int ch=0; ch<8; ch++){
      qh[ch] = *(const short8*)(qhi + qoff + ch*32);
      ql[ch] = *(const short8*)(qlo + qoff + ch*32);
    }
  }

  f32x4 o_acc[16];
  #pragma unroll
  for (int i=0;i<16;i++){ o_acc[i][0]=0.f; o_acc[i][1]=0.f; o_acc[i][2]=0.f; o_acc[i][3]=0.f; }
  float mst = -1e30f;   // running row max (raw score units)
  float lst = 0.f;      // running denominator

  const int swzK = (col & 7) << 4;
  const int g16  = g << 4;
  const int kb0  = col * 512;
  const int kb1  = kb0 + 8192;
  const int vb   = col*64 + (g16 ^ (((col>>1)&3)<<4));

  const int laneA  = col + ((g & 1) ? 32 : 0);
  const int laneB  = laneA + 16;
  const bool selLow = (g < 2);

  // staging source offsets (pre-swizzled so linear gload_lds dest => swizzled LDS)
  int ksrc[4], vsrc[4];
  #pragma unroll
  for (int i=0;i<4;i++){
    int s = w*4 + i;
    int L = s*1024 + lane*16;
    int m = L >> 9;
    ksrc[i] = m*512 + (((lane & 31)*16) ^ ((m & 7) << 4));
    int c = L >> 6;
    vsrc[i] = c*8192 + (((lane & 3)*16) ^ (((lane >> 3) & 3) << 4));
  }

  const char* khg = (const char*)(khi + ((size_t)b*4096)*256);
  const char* klg = (const char*)(klo + ((size_t)b*4096)*256);
  const char* vg  = (const char*)(vt  + ((size_t)b*256)*4096);

  // prologue: stage tile 0 into buf 0
  #pragma unroll
  for (int i=0;i<4;i++){
    int s = w*4 + i;
    GLOAD16(khg + ksrc[i], (char*)&kh_s[0][0] + s*1024);
    GLOAD16(klg + ksrc[i], (char*)&kl_s[0][0] + s*1024);
    GLOAD16(vg  + vsrc[i], (char*)&v_s [0][0] + s*1024);
  }

  int buf = 0;
  for (int it=0; it<128; ++it){
    __syncthreads();   // tile `it` staged (drains own gload_lds vmcnt + barrier)

    if (it < 127){     // prefetch next tile AFTER barrier -> overlaps compute
      const char* kht = khg + (size_t)(it+1)*16384;
      const char* klt = klg + (size_t)(it+1)*16384;
      const char* vtt = vg  + (size_t)(it+1)*64;
      #pragma unroll
      for (int i=0;i<4;i++){
        int s = w*4 + i;
        GLOAD16(kht + ksrc[i], (char*)&kh_s[buf^1][0] + s*1024);
        GLOAD16(klt + ksrc[i], (char*)&kl_s[buf^1][0] + s*1024);
        GLOAD16(vtt + vsrc[i], (char*)&v_s [buf^1][0] + s*1024);
      }
    }

    const char* khb  = (const char*)&kh_s[buf][0];
    const char* klb  = (const char*)&kl_s[buf][0];
    const char* vbuf = (const char*)&v_s [buf][0];

    // ---- QK^T (swapped): S^T[m][n] = sum_c K[m,c] Q[n,c], 3-term split
    f32x4 s0 = {0.f,0.f,0.f,0.f};
    f32x4 s1 = {0.f,0.f,0.f,0.f};
    #pragma unroll
    for (int ch=0; ch<8; ch++){
      int inr = ((ch << 6) | g16) ^ swzK;
      short8 kh0 = *(const short8*)(khb + kb0 + inr);
      short8 kh1 = *(const short8*)(khb + kb1 + inr);
      short8 kl0 = *(const short8*)(klb + kb0 + inr);
      short8 kl1 = *(const short8*)(klb + kb1 + inr);
      s0 = MFMA16(kh0, qh[ch], s0);
      s1 = MFMA16(kh1, qh[ch], s1);
      s0 = MFMA16(kh0, ql[ch], s0);
      s1 = MFMA16(kh1, ql[ch], s1);
      s0 = MFMA16(kl0, qh[ch], s0);
      s1 = MFMA16(kl1, qh[ch], s1);
    }

    // ---- online softmax over m (lane holds 8 m-values of one n-column)
    float tmax = fmaxf(fmaxf(fmaxf(s0[0],s0[1]), fmaxf(s0[2],s0[3])),
                       fmaxf(fmaxf(s1[0],s1[1]), fmaxf(s1[2],s1[3])));
    tmax = fmaxf(tmax, __shfl_xor(tmax, 16));
    tmax = fmaxf(tmax, __shfl_xor(tmax, 32));

    if (__any(tmax > mst)){
      float mnew = fmaxf(mst, tmax);
      float sc = exp2_fast((mst - mnew) * LOG2E);
      lst *= sc;
      #pragma unroll
      for (int i=0;i<16;i++){
        o_acc[i][0]*=sc; o_acc[i][1]*=sc; o_acc[i][2]*=sc; o_acc[i][3]*=sc;
      }
      mst = mnew;
    }
    const float mb = mst * LOG2E;
    float p0 = exp2_fast(s0[0]*LOG2E - mb);
    float p1 = exp2_fast(s0[1]*LOG2E - mb);
    float p2 = exp2_fast(s0[2]*LOG2E - mb);
    float p3 = exp2_fast(s0[3]*LOG2E - mb);
    float p4 = exp2_fast(s1[0]*LOG2E - mb);
    float p5 = exp2_fast(s1[1]*LOG2E - mb);
    float p6 = exp2_fast(s1[2]*LOG2E - mb);
    float p7 = exp2_fast(s1[3]*LOG2E - mb);

    float psum = ((p0+p1)+(p2+p3)) + ((p4+p5)+(p6+p7));
    psum += __shfl_xor(psum, 16);
    psum += __shfl_xor(psum, 32);
    lst  += psum;

    // ---- P -> PV B-fragment: pack bf16 pairs, cross-group transpose via bpermute
    int W0 = cvt_pk_bf16(p0, p1);   // m {4g, 4g+1}
    int W1 = cvt_pk_bf16(p2, p3);   // m {4g+2, 4g+3}
    int W2 = cvt_pk_bf16(p4, p5);   // m {16+4g, 16+4g+1}
    int W3 = cvt_pk_bf16(p6, p7);   // m {16+4g+2, 16+4g+3}

    int a0 = __shfl(W0, laneA), a1 = __shfl(W1, laneA);
    int a2 = __shfl(W2, laneA), a3 = __shfl(W3, laneA);
    int b0 = __shfl(W0, laneB), b1 = __shfl(W1, laneB);
    int b2 = __shfl(W2, laneB), b3 = __shfl(W3, laneB);
    int4v ti;
    ti[0] = selLow ? a0 : a2;
    ti[1] = selLow ? a1 : a3;
    ti[2] = selLow ? b0 : b2;
    ti[3] = selLow ? b1 : b3;
    short8 pf = __builtin_bit_cast(short8, ti);   // P[n][m = g*8 + j]

    // ---- PV: O^T[c][n] += sum_m V[m,c] P[n,m]
    #pragma unroll
    for (int ct=0; ct<16; ct++){
      short8 vf = *(const short8*)(vbuf + ct*1024 + vb);
      o_acc[ct] = MFMA16(vf, pf, o_acc[ct]);
    }

    buf ^= 1;
  }

  // ---- epilogue: normalize, write out[b, c, n] (coalesced along n)
  float rl = 1.0f / lst;
  const int outn = n0 + w*16 + col;
  #pragma unroll
  for (int ct=0; ct<16; ct++){
    #pragma unroll
    for (int r=0;r<4;r++){
      int c = ct*16 + g*4 + r;
      out[((size_t)(b*256 + c))*4096 + outn] = o_acc[ct][r] * rl;
    }
  }
}

// ---------------------------------------------------------------- launch
extern "C" void kernel_launch(void* const* d_in, const int* in_sizes, int n_in,
                              void* d_out, int out_size, void* d_ws, size_t ws_size,
                              hipStream_t stream)
{
  const float* x  = (const float*)d_in[0];
  const float* y  = (const float*)d_in[1];
  const float* Wq = (const float*)d_in[2];
  const float* bq = (const float*)d_in[3];
  const float* Wk = (const float*)d_in[4];
  const float* bk = (const float*)d_in[5];
  const float* Wv = (const float*)d_in[6];
  const float* bv = (const float*)d_in[7];
  float* out = (float*)d_out;

  char* ws = (char*)d_ws;
  const size_t MB = 1048576;
  unsigned short* qhi = (unsigned short*)(ws + 0*MB);
  unsigned short* qlo = (unsigned short*)(ws + 8*MB);
  unsigned short* khi = (unsigned short*)(ws + 16*MB);
  unsigned short* klo = (unsigned short*)(ws + 24*MB);
  unsigned short* vtb = (unsigned short*)(ws + 32*MB);
  float*          wt  = (float*)(ws + 40*MB);

  transpose_w<<<dim3(256,3), dim3(256), 0, stream>>>(Wq, Wk, Wv, wt);
  proj_kernel<<<dim3(64,4,3), dim3(256), 0, stream>>>(x, y, wt, bq, bk, bv,
                                                      qhi, qlo, khi, klo, vtb);
  attn_kernel<<<dim3(64,4), dim3(256), 0, stream>>>(qhi, qlo, khi, klo, vtb, out);
}

// Round 3
// 288.755 us; speedup vs baseline: 1.5396x; 1.5396x over previous
//
#include <hip/hip_runtime.h>

// CrossAttention: B=4, C=256, H=W=64, N=4096, fp32 in/out.
// f16 pipeline: Qf16 [B,N,C] @0MB, Kf16 [B,N,C] @8MB, Vt f16 [B,C,N] @16MB, WT f32 [3][C][C] @24MB

typedef __attribute__((ext_vector_type(8))) short short8;
typedef __attribute__((ext_vector_type(4))) short short4v;
typedef __attribute__((ext_vector_type(4))) float f32x4;
typedef __attribute__((ext_vector_type(4))) int int4v;
typedef __attribute__((ext_vector_type(8))) _Float16 half8;

#define LOG2E 1.44269504089f

static __device__ __forceinline__ float exp2_fast(float x){ return __builtin_amdgcn_exp2f(x); }

static __device__ __forceinline__ int pk_f16(float a, float b){
  auto h = __builtin_amdgcn_cvt_pkrtz(a, b);   // v_cvt_pkrtz_f16_f32: low=a, high=b
  return __builtin_bit_cast(int, h);
}
static __device__ __forceinline__ unsigned short f2h(float v){
  return __builtin_bit_cast(unsigned short, (_Float16)v);   // v_cvt_f16_f32 RNE
}

#define GLOAD16(gp, lp) __builtin_amdgcn_global_load_lds( \
  (const __attribute__((address_space(1))) void*)(gp),    \
  (__attribute__((address_space(3))) void*)(lp), 16, 0, 0)

#define MFMAF16(a,b,c) __builtin_amdgcn_mfma_f32_16x16x32_f16( \
  __builtin_bit_cast(half8, a), __builtin_bit_cast(half8, b), c, 0, 0, 0)

// ---------------------------------------------------------------- transpose W
__global__ __launch_bounds__(256) void transpose_w(
    const float* __restrict__ wq, const float* __restrict__ wk,
    const float* __restrict__ wv, float* __restrict__ wt)
{
  const int o = blockIdx.x;          // 0..255
  const int t = blockIdx.y;          // 0..2
  const int c = threadIdx.x;         // 0..255
  const float* w = (t == 0) ? wq : ((t == 1) ? wk : wv);
  wt[t*65536 + c*256 + o] = w[o*256 + c];   // WT[t][c][o] = W[o][c]
}

// ---------------------------------------------------------------- projections
// q[b,n,o] = sum_c Wq[o,c] x[b,c,n] + bq[o]  (k,v from y). fp32 VALU, f16 out.
// x-tile [256c x 64n] fp32 staged to LDS once; W streamed from L2.
__global__ __launch_bounds__(256) void proj_kernel(
    const float* __restrict__ x, const float* __restrict__ y,
    const float* __restrict__ wt,
    const float* __restrict__ bq, const float* __restrict__ bk, const float* __restrict__ bv,
    unsigned short* __restrict__ qf, unsigned short* __restrict__ kf,
    unsigned short* __restrict__ vtf)
{
  __shared__ float xs[256*64];   // 64KB: [c][n] fp32

  const int t   = blockIdx.z;
  const int b   = blockIdx.y;
  const int n0  = blockIdx.x * 64;
  const int tid = threadIdx.x;
  const int oi  = tid & 63;      // o = oi*4+a
  const int gq  = tid >> 6;      // wave id; n = n0 + gq*16 + j
  const int lane = tid & 63;

  const float* src = ((t == 0) ? x : y) + (size_t)b*1048576 + n0;

  // stage x-tile: 64KB, coalesced 256B row bursts, linear LDS dest
  #pragma unroll
  for (int i = 0; i < 16; i++){
    int seg = i*4 + gq;          // 1KB segment per wave per iter
    GLOAD16((const char*)src + (size_t)(seg*4 + (lane>>4))*16384 + (lane&15)*16,
            (char*)xs + seg*1024);
  }
  __syncthreads();

  const float* wrow = wt + t*65536 + oi*4;
  const float* bias = (t == 0) ? bq : ((t == 1) ? bk : bv);
  f32x4 bias4 = *(const f32x4*)&bias[oi*4];

  float acc[4][16];
  #pragma unroll
  for (int a=0;a<4;a++)
    #pragma unroll
    for (int j=0;j<16;j++) acc[a][j] = 0.f;

  const float* xr = xs + gq*16;
  #pragma unroll 4
  for (int c = 0; c < 256; c++){
    f32x4 wv4 = *(const f32x4*)&wrow[c*256];
    f32x4 xv0 = *(const f32x4*)&xr[c*64 + 0];
    f32x4 xv1 = *(const f32x4*)&xr[c*64 + 4];
    f32x4 xv2 = *(const f32x4*)&xr[c*64 + 8];
    f32x4 xv3 = *(const f32x4*)&xr[c*64 + 12];
    #pragma unroll
    for (int a=0;a<4;a++){
      float wa = wv4[a];
      #pragma unroll
      for (int j=0;j<4;j++){
        acc[a][j]    += wa * xv0[j];
        acc[a][4+j]  += wa * xv1[j];
        acc[a][8+j]  += wa * xv2[j];
        acc[a][12+j] += wa * xv3[j];
      }
    }
  }

  if (t < 2){
    unsigned short* outp = (t == 0) ? qf : kf;
    #pragma unroll
    for (int j=0;j<16;j++){
      int n = n0 + gq*16 + j;
      short4v hv;
      #pragma unroll
      for (int a=0;a<4;a++) hv[a] = (short)f2h(acc[a][j] + bias4[a]);
      *(short4v*)&outp[((size_t)(b*4096 + n))*256 + oi*4] = hv;
    }
  } else {
    #pragma unroll
    for (int a=0;a<4;a++){
      int o = oi*4 + a;
      float bb = bias4[a];
      short8 v0, v1;
      #pragma unroll
      for (int j=0;j<8;j++){
        v0[j] = (short)f2h(acc[a][j]   + bb);
        v1[j] = (short)f2h(acc[a][8+j] + bb);
      }
      size_t off = ((size_t)(b*256 + o))*4096 + n0 + gq*16;
      *(short8*)&vtf[off]     = v0;
      *(short8*)&vtf[off + 8] = v1;
    }
  }
}

// ---------------------------------------------------------------- attention
// grid (64 n-tiles, 4 batches), 256 thr = 4 waves x 16 q-rows. f16 QK + f16 PV.
// LDS 64KB -> 2 blocks/CU (2 waves/SIMD). KV tile 32, double-buffered,
// global_load_lds staging with XOR-pre-swizzled sources.
__global__ __launch_bounds__(256, 2) void attn_kernel(
    const unsigned short* __restrict__ qf, const unsigned short* __restrict__ kf,
    const unsigned short* __restrict__ vtf,
    float* __restrict__ out)
{
  __shared__ short kh_s[2][32*256];   // [buf][m][c] f16, rows 512B, swz ^((m&7)<<4)
  __shared__ short v_s [2][256*32];   // [buf][c][m] f16, rows 64B,  swz ^(((c>>1)&3)<<4)

  const int tid  = threadIdx.x;
  const int w    = tid >> 6;
  const int lane = tid & 63;
  const int g    = lane >> 4;
  const int col  = lane & 15;          // this lane's n (MFMA B-col) / c-row for V
  const int b    = blockIdx.y;
  const int n0   = blockIdx.x * 64;

  // Q fragments: Q[n][c], n = n0+w*16+col, 8 contiguous c per chunk
  short8 qh[8];
  {
    const size_t qoff = ((size_t)(b*4096 + n0 + w*16 + col))*256 + g*8;
    #pragma unroll
    for (int ch=0; ch<8; ch++)
      qh[ch] = *(const short8*)(qf + qoff + ch*32);
  }

  f32x4 o_acc[16];
  #pragma unroll
  for (int i=0;i<16;i++){ o_acc[i][0]=0.f; o_acc[i][1]=0.f; o_acc[i][2]=0.f; o_acc[i][3]=0.f; }
  float mst = -1e30f;   // running row max
  float lst = 0.f;      // running denominator

  const int swzK = (col & 7) << 4;
  const int g16  = g << 4;
  const int kb0  = col * 512;
  const int kb1  = kb0 + 8192;
  const int vb   = col*64 + (g16 ^ (((col>>1)&3)<<4));

  const int laneA  = col + ((g & 1) ? 32 : 0);
  const int laneB  = laneA + 16;
  const bool selLow = (g < 2);

  // staging source offsets (pre-swizzled so linear gload_lds dest => swizzled LDS)
  int ksrc[4], vsrc[4];
  #pragma unroll
  for (int i=0;i<4;i++){
    int s = w*4 + i;
    int L = s*1024 + lane*16;
    int m = L >> 9;
    ksrc[i] = m*512 + (((lane & 31)*16) ^ ((m & 7) << 4));
    int c = L >> 6;
    vsrc[i] = c*8192 + (((lane & 3)*16) ^ (((lane >> 3) & 3) << 4));
  }

  const char* khg = (const char*)(kf  + ((size_t)b*4096)*256);
  const char* vg  = (const char*)(vtf + ((size_t)b*256)*4096);

  // prologue: stage tile 0 into buf 0
  #pragma unroll
  for (int i=0;i<4;i++){
    int s = w*4 + i;
    GLOAD16(khg + ksrc[i], (char*)&kh_s[0][0] + s*1024);
    GLOAD16(vg  + vsrc[i], (char*)&v_s [0][0] + s*1024);
  }

  int buf = 0;
  for (int it=0; it<128; ++it){
    __syncthreads();   // tile `it` staged (vmcnt drained before s_barrier)

    if (it < 127){     // prefetch next tile AFTER barrier -> overlaps compute
      const char* kht = khg + (size_t)(it+1)*16384;
      const char* vtt = vg  + (size_t)(it+1)*64;
      #pragma unroll
      for (int i=0;i<4;i++){
        int s = w*4 + i;
        GLOAD16(kht + ksrc[i], (char*)&kh_s[buf^1][0] + s*1024);
        GLOAD16(vtt + vsrc[i], (char*)&v_s [buf^1][0] + s*1024);
      }
    }

    const char* khb  = (const char*)&kh_s[buf][0];
    const char* vbuf = (const char*)&v_s [buf][0];

    // ---- QK^T (swapped): S^T[m][n] = sum_c K[m,c] Q[n,c], single f16 term
    f32x4 s0 = {0.f,0.f,0.f,0.f};
    f32x4 s1 = {0.f,0.f,0.f,0.f};
    #pragma unroll
    for (int ch=0; ch<8; ch++){
      int inr = ((ch << 6) | g16) ^ swzK;
      short8 kh0 = *(const short8*)(khb + kb0 + inr);
      short8 kh1 = *(const short8*)(khb + kb1 + inr);
      s0 = MFMAF16(kh0, qh[ch], s0);
      s1 = MFMAF16(kh1, qh[ch], s1);
    }

    // ---- online softmax over m (lane holds 8 m-values of one n-column)
    float tmax = fmaxf(fmaxf(fmaxf(s0[0],s0[1]), fmaxf(s0[2],s0[3])),
                       fmaxf(fmaxf(s1[0],s1[1]), fmaxf(s1[2],s1[3])));
    tmax = fmaxf(tmax, __shfl_xor(tmax, 16));
    tmax = fmaxf(tmax, __shfl_xor(tmax, 32));

    if (__any(tmax > mst)){
      float mnew = fmaxf(mst, tmax);
      float sc = exp2_fast((mst - mnew) * LOG2E);
      lst *= sc;
      #pragma unroll
      for (int i=0;i<16;i++){
        o_acc[i][0]*=sc; o_acc[i][1]*=sc; o_acc[i][2]*=sc; o_acc[i][3]*=sc;
      }
      mst = mnew;
    }
    const float mb = mst * LOG2E;
    float p0 = exp2_fast(s0[0]*LOG2E - mb);
    float p1 = exp2_fast(s0[1]*LOG2E - mb);
    float p2 = exp2_fast(s0[2]*LOG2E - mb);
    float p3 = exp2_fast(s0[3]*LOG2E - mb);
    float p4 = exp2_fast(s1[0]*LOG2E - mb);
    float p5 = exp2_fast(s1[1]*LOG2E - mb);
    float p6 = exp2_fast(s1[2]*LOG2E - mb);
    float p7 = exp2_fast(s1[3]*LOG2E - mb);

    float psum = ((p0+p1)+(p2+p3)) + ((p4+p5)+(p6+p7));
    psum += __shfl_xor(psum, 16);
    psum += __shfl_xor(psum, 32);
    lst  += psum;

    // ---- P -> PV B-fragment: pack f16 pairs, cross-group transpose via shfl
    int W0 = pk_f16(p0, p1);   // m {4g, 4g+1}
    int W1 = pk_f16(p2, p3);   // m {4g+2, 4g+3}
    int W2 = pk_f16(p4, p5);   // m {16+4g, 16+4g+1}
    int W3 = pk_f16(p6, p7);   // m {16+4g+2, 16+4g+3}

    int a0 = __shfl(W0, laneA), a1 = __shfl(W1, laneA);
    int a2 = __shfl(W2, laneA), a3 = __shfl(W3, laneA);
    int b0 = __shfl(W0, laneB), b1 = __shfl(W1, laneB);
    int b2 = __shfl(W2, laneB), b3 = __shfl(W3, laneB);
    int4v ti;
    ti[0] = selLow ? a0 : a2;
    ti[1] = selLow ? a1 : a3;
    ti[2] = selLow ? b0 : b2;
    ti[3] = selLow ? b1 : b3;
    short8 pf = __builtin_bit_cast(short8, ti);   // P[n][m = g*8 + j]

    // ---- PV: O^T[c][n] += sum_m V[m,c] P[n,m]
    #pragma unroll
    for (int ct=0; ct<16; ct++){
      short8 vf = *(const short8*)(vbuf + ct*1024 + vb);
      o_acc[ct] = MFMAF16(vf, pf, o_acc[ct]);
    }

    buf ^= 1;
  }

  // ---- epilogue: normalize, write out[b, c, n] (coalesced along n)
  float rl = 1.0f / lst;
  const int outn = n0 + w*16 + col;
  #pragma unroll
  for (int ct=0; ct<16; ct++){
    #pragma unroll
    for (int r=0;r<4;r++){
      int c = ct*16 + g*4 + r;
      out[((size_t)(b*256 + c))*4096 + outn] = o_acc[ct][r] * rl;
    }
  }
}

// ---------------------------------------------------------------- launch
extern "C" void kernel_launch(void* const* d_in, const int* in_sizes, int n_in,
                              void* d_out, int out_size, void* d_ws, size_t ws_size,
                              hipStream_t stream)
{
  const float* x  = (const float*)d_in[0];
  const float* y  = (const float*)d_in[1];
  const float* Wq = (const float*)d_in[2];
  const float* bq = (const float*)d_in[3];
  const float* Wk = (const float*)d_in[4];
  const float* bk = (const float*)d_in[5];
  const float* Wv = (const float*)d_in[6];
  const float* bv = (const float*)d_in[7];
  float* out = (float*)d_out;

  char* ws = (char*)d_ws;
  const size_t MB = 1048576;
  unsigned short* qf  = (unsigned short*)(ws + 0*MB);
  unsigned short* kfp = (unsigned short*)(ws + 8*MB);
  unsigned short* vtf = (unsigned short*)(ws + 16*MB);
  float*          wt  = (float*)(ws + 24*MB);

  transpose_w<<<dim3(256,3), dim3(256), 0, stream>>>(Wq, Wk, Wv, wt);
  proj_kernel<<<dim3(64,4,3), dim3(256), 0, stream>>>(x, y, wt, bq, bk, bv,
                                                      qf, kfp, vtf);
  attn_kernel<<<dim3(64,4), dim3(256), 0, stream>>>(qf, kfp, vtf, out);
}

// Round 4
// 244.145 us; speedup vs baseline: 1.8209x; 1.1827x over previous
//
#include <hip/hip_runtime.h>

// CrossAttention: B=4, C=256, H=W=64, N=4096, fp32 in/out.
// f16 pipeline: Qf16 [B,N,C] @0MB, Kf16 [B,N,C] @8MB, Vt f16 [B,C,N] @16MB, WT f32 [3][C][C] @24MB

typedef __attribute__((ext_vector_type(8))) short short8;
typedef __attribute__((ext_vector_type(4))) short short4v;
typedef __attribute__((ext_vector_type(4))) float f32x4;
typedef __attribute__((ext_vector_type(4))) int int4v;
typedef __attribute__((ext_vector_type(8))) _Float16 half8;

#define LOG2E 1.44269504089f

static __device__ __forceinline__ float exp2_fast(float x){ return __builtin_amdgcn_exp2f(x); }

static __device__ __forceinline__ int pk_f16(float a, float b){
  auto h = __builtin_amdgcn_cvt_pkrtz(a, b);   // v_cvt_pkrtz_f16_f32: low=a, high=b
  return __builtin_bit_cast(int, h);
}
static __device__ __forceinline__ unsigned short f2h(float v){
  return __builtin_bit_cast(unsigned short, (_Float16)v);   // v_cvt_f16_f32 RNE
}

#define GLOAD16(gp, lp) __builtin_amdgcn_global_load_lds( \
  (const __attribute__((address_space(1))) void*)(gp),    \
  (__attribute__((address_space(3))) void*)(lp), 16, 0, 0)

#define MFMAF16(a,b,c) __builtin_amdgcn_mfma_f32_16x16x32_f16( \
  __builtin_bit_cast(half8, a), __builtin_bit_cast(half8, b), c, 0, 0, 0)

// ---------------------------------------------------------------- transpose W
__global__ __launch_bounds__(256) void transpose_w(
    const float* __restrict__ wq, const float* __restrict__ wk,
    const float* __restrict__ wv, float* __restrict__ wt)
{
  const int o = blockIdx.x;          // 0..255
  const int t = blockIdx.y;          // 0..2
  const int c = threadIdx.x;         // 0..255
  const float* w = (t == 0) ? wq : ((t == 1) ? wk : wv);
  wt[t*65536 + c*256 + o] = w[o*256 + c];   // WT[t][c][o] = W[o][c]
}

// ---------------------------------------------------------------- projections
// q[b,n,o] = sum_c Wq[o,c] x[b,c,n] + bq[o]  (k,v from y). fp32 VALU, f16 out.
// x-tile staged in two 32KB halves (LDS 32KB -> 3 blocks/CU co-resident).
__global__ __launch_bounds__(256) void proj_kernel(
    const float* __restrict__ x, const float* __restrict__ y,
    const float* __restrict__ wt,
    const float* __restrict__ bq, const float* __restrict__ bk, const float* __restrict__ bv,
    unsigned short* __restrict__ qf, unsigned short* __restrict__ kf,
    unsigned short* __restrict__ vtf)
{
  __shared__ float xs[128*64];   // 32KB: [c][n] fp32 (half of the c range)

  const int t   = blockIdx.z;
  const int b   = blockIdx.y;
  const int n0  = blockIdx.x * 64;
  const int tid = threadIdx.x;
  const int oi  = tid & 63;      // o = oi*4+a
  const int gq  = tid >> 6;      // wave id; n = n0 + gq*16 + j
  const int lane = tid & 63;

  const float* src = ((t == 0) ? x : y) + (size_t)b*1048576 + n0;

  const float* wrow = wt + t*65536 + oi*4;
  const float* bias = (t == 0) ? bq : ((t == 1) ? bk : bv);
  f32x4 bias4 = *(const f32x4*)&bias[oi*4];

  float acc[4][16];
  #pragma unroll
  for (int a=0;a<4;a++)
    #pragma unroll
    for (int j=0;j<16;j++) acc[a][j] = 0.f;

  const float* xr = xs + gq*16;

  for (int half = 0; half < 2; half++){
    if (half) __syncthreads();   // prior compute done before overwrite
    // stage 128c x 64n fp32 = 32KB, coalesced 256B rows, linear LDS dest
    #pragma unroll
    for (int i = 0; i < 8; i++){
      int seg = i*4 + gq;        // 1KB segment per wave per iter
      GLOAD16((const char*)src + (size_t)(half*128 + seg*4 + (lane>>4))*16384 + (lane&15)*16,
              (char*)xs + seg*1024);
    }
    __syncthreads();

    const float* wh = wrow + half*128*256;
    #pragma unroll 4
    for (int c = 0; c < 128; c++){
      f32x4 wv4 = *(const f32x4*)&wh[c*256];
      f32x4 xv0 = *(const f32x4*)&xr[c*64 + 0];
      f32x4 xv1 = *(const f32x4*)&xr[c*64 + 4];
      f32x4 xv2 = *(const f32x4*)&xr[c*64 + 8];
      f32x4 xv3 = *(const f32x4*)&xr[c*64 + 12];
      #pragma unroll
      for (int a=0;a<4;a++){
        float wa = wv4[a];
        #pragma unroll
        for (int j=0;j<4;j++){
          acc[a][j]    += wa * xv0[j];
          acc[a][4+j]  += wa * xv1[j];
          acc[a][8+j]  += wa * xv2[j];
          acc[a][12+j] += wa * xv3[j];
        }
      }
    }
  }

  if (t < 2){
    unsigned short* outp = (t == 0) ? qf : kf;
    #pragma unroll
    for (int j=0;j<16;j++){
      int n = n0 + gq*16 + j;
      short4v hv;
      #pragma unroll
      for (int a=0;a<4;a++) hv[a] = (short)f2h(acc[a][j] + bias4[a]);
      *(short4v*)&outp[((size_t)(b*4096 + n))*256 + oi*4] = hv;
    }
  } else {
    #pragma unroll
    for (int a=0;a<4;a++){
      int o = oi*4 + a;
      float bb = bias4[a];
      short8 v0, v1;
      #pragma unroll
      for (int j=0;j<8;j++){
        v0[j] = (short)f2h(acc[a][j]   + bb);
        v1[j] = (short)f2h(acc[a][8+j] + bb);
      }
      size_t off = ((size_t)(b*256 + o))*4096 + n0 + gq*16;
      *(short8*)&vtf[off]     = v0;
      *(short8*)&vtf[off + 8] = v1;
    }
  }
}

// ---------------------------------------------------------------- attention
// grid (64 n-tiles, 4 batches), 512 thr = 2 KV-groups x 4 q-waves.
// Group h processes KV tiles [h*64, h*64+64), own double-buffered K/V LDS
// (128KB total). Group 1 publishes (m,l,O) via LDS; group 0 merges + writes.
// 8 waves/block = 2 waves/SIMD (one from each group -> phase diversity).
__global__ __launch_bounds__(512, 2) void attn_kernel(
    const unsigned short* __restrict__ qf, const unsigned short* __restrict__ kf,
    const unsigned short* __restrict__ vtf,
    float* __restrict__ out)
{
  __shared__ short kh_s[2][2][32*256];   // [half][buf][m][c] f16, swz ^((m&7)<<4)
  __shared__ short v_s [2][2][256*32];   // [half][buf][c][m] f16, swz ^(((c>>1)&3)<<4)

  const int tid  = threadIdx.x;
  const int w    = tid >> 6;           // 0..7
  const int h    = w >> 2;             // KV half
  const int wq   = w & 3;              // q sub-tile
  const int lane = tid & 63;
  const int g    = lane >> 4;
  const int col  = lane & 15;          // this lane's n (MFMA B-col) / c-row for V
  const int b    = blockIdx.y;
  const int n0   = blockIdx.x * 64;

  // Q fragments: Q[n][c], n = n0+wq*16+col, 8 contiguous c per chunk
  short8 qh[8];
  {
    const size_t qoff = ((size_t)(b*4096 + n0 + wq*16 + col))*256 + g*8;
    #pragma unroll
    for (int ch=0; ch<8; ch++)
      qh[ch] = *(const short8*)(qf + qoff + ch*32);
  }

  f32x4 o_acc[16];
  #pragma unroll
  for (int i=0;i<16;i++){ o_acc[i][0]=0.f; o_acc[i][1]=0.f; o_acc[i][2]=0.f; o_acc[i][3]=0.f; }
  float mst = -1e30f;   // running row max
  float lst = 0.f;      // running denominator

  const int swzK = (col & 7) << 4;
  const int g16  = g << 4;
  const int kb0  = col * 512;
  const int kb1  = kb0 + 8192;
  const int vb   = col*64 + (g16 ^ (((col>>1)&3)<<4));

  const int laneA  = col + ((g & 1) ? 32 : 0);
  const int laneB  = laneA + 16;
  const bool selLow = (g < 2);

  // staging source offsets (pre-swizzled so linear gload_lds dest => swizzled LDS)
  int ksrc[4], vsrc[4];
  #pragma unroll
  for (int i=0;i<4;i++){
    int s = wq*4 + i;
    int L = s*1024 + lane*16;
    int m = L >> 9;
    ksrc[i] = m*512 + (((lane & 31)*16) ^ ((m & 7) << 4));
    int c = L >> 6;
    vsrc[i] = c*8192 + (((lane & 3)*16) ^ (((lane >> 3) & 3) << 4));
  }

  const char* khg = (const char*)(kf  + ((size_t)b*4096)*256) + (size_t)h*64*16384;
  const char* vg  = (const char*)(vtf + ((size_t)b*256)*4096) + (size_t)h*64*64;

  // prologue: stage this group's tile 0 into buf 0
  #pragma unroll
  for (int i=0;i<4;i++){
    int s = wq*4 + i;
    GLOAD16(khg + ksrc[i], (char*)&kh_s[h][0][0] + s*1024);
    GLOAD16(vg  + vsrc[i], (char*)&v_s [h][0][0] + s*1024);
  }

  int buf = 0;
  for (int it=0; it<64; ++it){
    __syncthreads();   // tile staged (vmcnt drained before s_barrier)

    if (it < 63){      // prefetch next tile AFTER barrier -> overlaps compute
      const char* kht = khg + (size_t)(it+1)*16384;
      const char* vtt = vg  + (size_t)(it+1)*64;
      #pragma unroll
      for (int i=0;i<4;i++){
        int s = wq*4 + i;
        GLOAD16(kht + ksrc[i], (char*)&kh_s[h][buf^1][0] + s*1024);
        GLOAD16(vtt + vsrc[i], (char*)&v_s [h][buf^1][0] + s*1024);
      }
    }

    const char* khb  = (const char*)&kh_s[h][buf][0];
    const char* vbuf = (const char*)&v_s [h][buf][0];

    // ---- QK^T (swapped): S^T[m][n] = sum_c K[m,c] Q[n,c]
    f32x4 s0 = {0.f,0.f,0.f,0.f};
    f32x4 s1 = {0.f,0.f,0.f,0.f};
    __builtin_amdgcn_s_setprio(1);
    #pragma unroll
    for (int ch=0; ch<8; ch++){
      int inr = ((ch << 6) | g16) ^ swzK;
      short8 kh0 = *(const short8*)(khb + kb0 + inr);
      short8 kh1 = *(const short8*)(khb + kb1 + inr);
      s0 = MFMAF16(kh0, qh[ch], s0);
      s1 = MFMAF16(kh1, qh[ch], s1);
    }
    __builtin_amdgcn_s_setprio(0);

    // ---- online softmax over m (lane holds 8 m-values of one n-column)
    float tmax = fmaxf(fmaxf(fmaxf(s0[0],s0[1]), fmaxf(s0[2],s0[3])),
                       fmaxf(fmaxf(s1[0],s1[1]), fmaxf(s1[2],s1[3])));
    tmax = fmaxf(tmax, __shfl_xor(tmax, 16));
    tmax = fmaxf(tmax, __shfl_xor(tmax, 32));

    if (__any(tmax > mst)){
      float mnew = fmaxf(mst, tmax);
      float sc = exp2_fast((mst - mnew) * LOG2E);
      lst *= sc;
      #pragma unroll
      for (int i=0;i<16;i++){
        o_acc[i][0]*=sc; o_acc[i][1]*=sc; o_acc[i][2]*=sc; o_acc[i][3]*=sc;
      }
      mst = mnew;
    }
    const float mb = mst * LOG2E;
    float p0 = exp2_fast(s0[0]*LOG2E - mb);
    float p1 = exp2_fast(s0[1]*LOG2E - mb);
    float p2 = exp2_fast(s0[2]*LOG2E - mb);
    float p3 = exp2_fast(s0[3]*LOG2E - mb);
    float p4 = exp2_fast(s1[0]*LOG2E - mb);
    float p5 = exp2_fast(s1[1]*LOG2E - mb);
    float p6 = exp2_fast(s1[2]*LOG2E - mb);
    float p7 = exp2_fast(s1[3]*LOG2E - mb);

    float psum = ((p0+p1)+(p2+p3)) + ((p4+p5)+(p6+p7));
    psum += __shfl_xor(psum, 16);
    psum += __shfl_xor(psum, 32);
    lst  += psum;

    // ---- P -> PV B-fragment: pack f16 pairs, cross-group transpose via shfl
    int W0 = pk_f16(p0, p1);   // m {4g, 4g+1}
    int W1 = pk_f16(p2, p3);   // m {4g+2, 4g+3}
    int W2 = pk_f16(p4, p5);   // m {16+4g, 16+4g+1}
    int W3 = pk_f16(p6, p7);   // m {16+4g+2, 16+4g+3}

    int a0 = __shfl(W0, laneA), a1 = __shfl(W1, laneA);
    int a2 = __shfl(W2, laneA), a3 = __shfl(W3, laneA);
    int b0 = __shfl(W0, laneB), b1 = __shfl(W1, laneB);
    int b2 = __shfl(W2, laneB), b3 = __shfl(W3, laneB);
    int4v ti;
    ti[0] = selLow ? a0 : a2;
    ti[1] = selLow ? a1 : a3;
    ti[2] = selLow ? b0 : b2;
    ti[3] = selLow ? b1 : b3;
    short8 pf = __builtin_bit_cast(short8, ti);   // P[n][m = g*8 + j]

    // ---- PV: O^T[c][n] += sum_m V[m,c] P[n,m]
    __builtin_amdgcn_s_setprio(1);
    #pragma unroll
    for (int ct=0; ct<16; ct++){
      short8 vf = *(const short8*)(vbuf + ct*1024 + vb);
      o_acc[ct] = MFMAF16(vf, pf, o_acc[ct]);
    }
    __builtin_amdgcn_s_setprio(0);

    buf ^= 1;
  }

  // ---- merge the two KV halves via LDS, then group 0 writes out
  float* sm  = (float*)&v_s[0][0][0];    // 64KB: [wq][ct][lane] f32x4
  float* sml = (float*)&kh_s[0][0][0];   // 2KB: m,l per lane
  __syncthreads();                        // everyone done with K/V buffers
  if (h == 1){
    #pragma unroll
    for (int ct=0; ct<16; ct++)
      *(f32x4*)(sm + wq*4096 + ct*256 + lane*4) = o_acc[ct];
    sml[wq*128 + lane*2]     = mst;
    sml[wq*128 + lane*2 + 1] = lst;
  }
  __syncthreads();
  if (h == 0){
    float m1 = sml[wq*128 + lane*2];
    float l1 = sml[wq*128 + lane*2 + 1];
    float m  = fmaxf(mst, m1);
    float sc0 = exp2_fast((mst - m) * LOG2E);
    float sc1 = exp2_fast((m1  - m) * LOG2E);
    float rl  = 1.0f / (lst*sc0 + l1*sc1);
    sc0 *= rl; sc1 *= rl;

    const int outn = n0 + wq*16 + col;
    #pragma unroll
    for (int ct=0; ct<16; ct++){
      f32x4 o1 = *(f32x4*)(sm + wq*4096 + ct*256 + lane*4);
      #pragma unroll
      for (int r=0;r<4;r++){
        int c = ct*16 + g*4 + r;
        out[((size_t)(b*256 + c))*4096 + outn] = o_acc[ct][r]*sc0 + o1[r]*sc1;
      }
    }
  }
}

// ---------------------------------------------------------------- launch
extern "C" void kernel_launch(void* const* d_in, const int* in_sizes, int n_in,
                              void* d_out, int out_size, void* d_ws, size_t ws_size,
                              hipStream_t stream)
{
  const float* x  = (const float*)d_in[0];
  const float* y  = (const float*)d_in[1];
  const float* Wq = (const float*)d_in[2];
  const float* bq = (const float*)d_in[3];
  const float* Wk = (const float*)d_in[4];
  const float* bk = (const float*)d_in[5];
  const float* Wv = (const float*)d_in[6];
  const float* bv = (const float*)d_in[7];
  float* out = (float*)d_out;

  char* ws = (char*)d_ws;
  const size_t MB = 1048576;
  unsigned short* qf  = (unsigned short*)(ws + 0*MB);
  unsigned short* kfp = (unsigned short*)(ws + 8*MB);
  unsigned short* vtf = (unsigned short*)(ws + 16*MB);
  float*          wt  = (float*)(ws + 24*MB);

  transpose_w<<<dim3(256,3), dim3(256), 0, stream>>>(Wq, Wk, Wv, wt);
  proj_kernel<<<dim3(64,4,3), dim3(256), 0, stream>>>(x, y, wt, bq, bk, bv,
                                                      qf, kfp, vtf);
  attn_kernel<<<dim3(64,4), dim3(512), 0, stream>>>(qf, kfp, vtf, out);
}